// Round 2
// baseline (221.862 us; speedup 1.0000x reference)
//
#include <hip/hip_runtime.h>
#include <hip/hip_cooperative_groups.h>
#include <math.h>

namespace cg = cooperative_groups;

#define SS 8192
#define HH 2048
// W_att is (H, 2H) row-major, row stride 4096 floats. We only touch cols [H, 2H).
// hidden/b_att contribute a constant score shift -> cancels in softmax.

// ws layout: v2 = ws[0..2048), scores = ws[2048..2048+8192)

__global__ void __launch_bounds__(256, 1) fused_attn(
    const float* __restrict__ enc,
    const float* __restrict__ W,
    const float* __restrict__ w,
    float* __restrict__ out,
    float* __restrict__ ws)
{
    cg::grid_group grid = cg::this_grid();
    const int tid  = threadIdx.x;
    const int bid  = blockIdx.x;            // 0..255
    const int gtid = bid * 256 + tid;

    float* v2     = ws;                     // 2048 floats
    float* scores = ws + HH;                // 8192 floats

    // ---- phase 0: zero v2 ----
    if (gtid < HH) v2[gtid] = 0.0f;
    grid.sync();

    // ---- phase 1: v2[col] = sum_j w[j] * W[j, HH+col] ----
    {
        const int bx   = bid & 7;           // 8 column groups of 256
        const int by   = bid >> 3;          // 32 row groups of 64
        const int col  = bx * 256 + tid;
        const int row0 = by * 64;
        const float* base = W + (size_t)row0 * (2 * HH) + HH + col;
        float acc = 0.0f;
#pragma unroll 8
        for (int j = 0; j < 64; ++j)
            acc += w[row0 + j] * base[(size_t)j * (2 * HH)];
        atomicAdd(&v2[col], acc);
    }
    grid.sync();

    // ---- phase 2: scores[s] = enc[s,:] . v2  (1024 waves, 8 rows each) ----
    {
        const int wave = gtid >> 6;         // 0..1023
        const int lane = tid & 63;
        const float4* v = (const float4*)v2;
        float4 vb[8];
#pragma unroll
        for (int i = 0; i < 8; ++i) vb[i] = v[lane + i * 64];

        for (int rr = 0; rr < 8; ++rr) {
            const int row = wave * 8 + rr;
            const float4* e = (const float4*)(enc + (size_t)row * HH);
            float acc = 0.0f;
#pragma unroll
            for (int i = 0; i < 8; ++i) {
                float4 a = e[lane + i * 64];
                acc += a.x * vb[i].x + a.y * vb[i].y + a.z * vb[i].z + a.w * vb[i].w;
            }
#pragma unroll
            for (int off = 32; off > 0; off >>= 1)
                acc += __shfl_down(acc, off);
            if (lane == 0) scores[row] = acc;
        }
    }
    grid.sync();

    // ---- phase 3: softmax (block 0 only; 32 elems/thread) ----
    if (bid == 0) {
        __shared__ float red[4];
        const int lane = tid & 63;
        const int wid  = tid >> 6;          // 4 waves

        float vals[32];
        float m = -INFINITY;
#pragma unroll
        for (int i = 0; i < 32; ++i) {
            vals[i] = scores[tid + i * 256];
            m = fmaxf(m, vals[i]);
        }
#pragma unroll
        for (int off = 1; off < 64; off <<= 1)
            m = fmaxf(m, __shfl_xor(m, off));
        if (lane == 0) red[wid] = m;
        __syncthreads();
        m = fmaxf(fmaxf(red[0], red[1]), fmaxf(red[2], red[3]));

        float s = 0.0f;
#pragma unroll
        for (int i = 0; i < 32; ++i) {
            vals[i] = __expf(vals[i] - m);
            s += vals[i];
        }
#pragma unroll
        for (int off = 1; off < 64; off <<= 1)
            s += __shfl_xor(s, off);
        __syncthreads();
        if (lane == 0) red[wid] = s;
        __syncthreads();
        s = red[0] + red[1] + red[2] + red[3];

        const float inv = 1.0f / s;
#pragma unroll
        for (int i = 0; i < 32; ++i)
            out[tid + i * 256] = vals[i] * inv;
    }
}

extern "C" void kernel_launch(void* const* d_in, const int* in_sizes, int n_in,
                              void* d_out, int out_size, void* d_ws, size_t ws_size,
                              hipStream_t stream) {
    const float* enc   = (const float*)d_in[0];  // (S,1,H)
    // d_in[1] = hidden : constant shift, cancels in softmax
    const float* W_att = (const float*)d_in[2];  // (H, 2H)
    // d_in[3] = b_att  : constant shift, cancels
    const float* w     = (const float*)d_in[4];  // (1, H)

    float* out = (float*)d_out;
    float* ws  = (float*)d_ws;

    void* args[] = { (void*)&enc, (void*)&W_att, (void*)&w, (void*)&out, (void*)&ws };
    hipLaunchCooperativeKernel((void*)fused_attn, dim3(256), dim3(256), args, 0, stream);
}

// Round 3
// 209.070 us; speedup vs baseline: 1.0612x; 1.0612x over previous
//
#include <hip/hip_runtime.h>
#include <math.h>

#define SS 8192
#define HH 2048
// W_att is (H, 2H) row-major, row stride 4096 floats; only cols [H,2H) matter.
// hidden & b_att contribute a constant score shift -> cancels in softmax.
//
// ws layout (floats): v2 = ws[0..2048), counter = ((int*)ws)[2048],
//                     scores = ws[2560..2560+8192)
// memset covers ws[0..2560) = 10240 bytes.

__global__ void colsum_kernel(const float* __restrict__ W,
                              const float* __restrict__ w,
                              float* __restrict__ v2) {
    const int col  = (blockIdx.x & 7) * 256 + threadIdx.x;   // 0..2047
    const int row0 = (blockIdx.x >> 3) * 64;                 // 32 row groups
    const float* base = W + (size_t)row0 * (2 * HH) + HH + col;
    float acc = 0.0f;
#pragma unroll 8
    for (int j = 0; j < 64; ++j)
        acc += w[row0 + j] * base[(size_t)j * (2 * HH)];
    atomicAdd(&v2[col], acc);
}

// 2048 blocks x 256 threads: 4 waves/block, one row per wave (8192 rows).
// Last block to finish performs the softmax over all 8192 scores.
__global__ void __launch_bounds__(256) rowdot_softmax(
    const float* __restrict__ enc,
    float* __restrict__ ws,
    float* __restrict__ out)
{
    const float* v2 = ws;
    int* counter    = (int*)(ws + 2048);
    float* scores   = ws + 2560;

    const int wave = threadIdx.x >> 6;
    const int lane = threadIdx.x & 63;
    const int row  = blockIdx.x * 4 + wave;

    const float4* v = (const float4*)v2;
    const float4* e = (const float4*)(enc + (size_t)row * HH);
    float acc = 0.0f;
#pragma unroll
    for (int i = 0; i < 8; ++i) {          // 512 float4 / 64 lanes
        float4 a = e[lane + i * 64];
        float4 b = v[lane + i * 64];
        acc += a.x * b.x + a.y * b.y + a.z * b.z + a.w * b.w;
    }
#pragma unroll
    for (int off = 32; off > 0; off >>= 1)
        acc += __shfl_down(acc, off);
    if (lane == 0) scores[row] = acc;

    // ---- last-block softmax ----
    __shared__ int is_last;
    __syncthreads();
    if (threadIdx.x == 0) {
        __threadfence();                    // release our score writes
        int old = atomicAdd(counter, 1);    // device-scope
        is_last = (old == (int)gridDim.x - 1);
    }
    __syncthreads();
    if (!is_last) return;
    __threadfence();                        // acquire everyone's score writes

    __shared__ float red[4];
    const int tid = threadIdx.x;
    const int wid = tid >> 6;               // 4 waves

    float vals[32];
    float m = -INFINITY;
#pragma unroll
    for (int i = 0; i < 32; ++i) {
        vals[i] = scores[tid + i * 256];
        m = fmaxf(m, vals[i]);
    }
#pragma unroll
    for (int off = 1; off < 64; off <<= 1)
        m = fmaxf(m, __shfl_xor(m, off));
    if (lane == 0) red[wid] = m;
    __syncthreads();
    m = fmaxf(fmaxf(red[0], red[1]), fmaxf(red[2], red[3]));

    float s = 0.0f;
#pragma unroll
    for (int i = 0; i < 32; ++i) {
        vals[i] = __expf(vals[i] - m);
        s += vals[i];
    }
#pragma unroll
    for (int off = 1; off < 64; off <<= 1)
        s += __shfl_xor(s, off);
    __syncthreads();
    if (lane == 0) red[wid] = s;
    __syncthreads();
    s = red[0] + red[1] + red[2] + red[3];

    const float inv = 1.0f / s;
#pragma unroll
    for (int i = 0; i < 32; ++i)
        out[tid + i * 256] = vals[i] * inv;
}

extern "C" void kernel_launch(void* const* d_in, const int* in_sizes, int n_in,
                              void* d_out, int out_size, void* d_ws, size_t ws_size,
                              hipStream_t stream) {
    const float* enc   = (const float*)d_in[0];  // (S,1,H)
    // d_in[1] = hidden : constant score shift, cancels in softmax
    const float* W_att = (const float*)d_in[2];  // (H, 2H)
    // d_in[3] = b_att  : constant score shift, cancels
    const float* w     = (const float*)d_in[4];  // (1, H)

    float* out = (float*)d_out;                  // 8192 floats
    float* ws  = (float*)d_ws;

    hipMemsetAsync(ws, 0, 2560 * sizeof(float), stream);  // v2 + counter
    hipLaunchKernelGGL(colsum_kernel,  dim3(256),  dim3(256), 0, stream, W_att, w, ws);
    hipLaunchKernelGGL(rowdot_softmax, dim3(2048), dim3(256), 0, stream, enc, ws, out);
}

// Round 4
// 122.103 us; speedup vs baseline: 1.8170x; 1.7122x over previous
//
#include <hip/hip_runtime.h>
#include <math.h>

#define SS 8192
#define HH 2048
// W_att is (H, 2H) row-major, row stride 4096 floats; only cols [H,2H) matter.
// hidden & b_att add a constant score shift -> cancels in softmax.
//
// ws layout (floats): pp[2][2048] at ws[0..4096), scores at ws[4096..12288).
// No memset needed: every ws word is written before it is read.
// No atomics, no device fences anywhere (cross-XCD fences cost ~100us; dispatch
// boundaries give global ordering for free).

// grid 256 = (cg 0..127, rh 0..1). Block exclusively owns cols [16cg,16cg+16)
// and rows [1024*rh, 1024*rh+1024): pp[rh][col] = sum_rows w[row]*W[row][HH+col]
__global__ void __launch_bounds__(256) colsum_kernel(
    const float* __restrict__ W,
    const float* __restrict__ w,
    float* __restrict__ pp)
{
    const int cg = blockIdx.x & 127;
    const int rh = blockIdx.x >> 7;
    const int c4 = threadIdx.x & 3;        // float4 slot within the 16 cols
    const int rg = threadIdx.x >> 2;       // 64 row-groups of 16 rows
    const int col0 = cg * 16 + c4 * 4;
    const int row0 = rh * 1024 + rg * 16;

    const float* base = W + (size_t)row0 * (2 * HH) + HH + col0;
    float4 acc = make_float4(0.f, 0.f, 0.f, 0.f);
#pragma unroll
    for (int i = 0; i < 16; ++i) {
        const float wi = w[row0 + i];
        const float4 a = *(const float4*)(base + (size_t)i * (2 * HH));
        acc.x += wi * a.x; acc.y += wi * a.y;
        acc.z += wi * a.z; acc.w += wi * a.w;
    }

    __shared__ float4 lds[256];
    lds[threadIdx.x] = acc;
    __syncthreads();
    // tree over row-groups; all offsets are multiples of 4 so c4 lanes never mix
    for (int off = 128; off >= 4; off >>= 1) {
        if (threadIdx.x < off) {
            float4 o = lds[threadIdx.x + off];
            float4 m = lds[threadIdx.x];
            m.x += o.x; m.y += o.y; m.z += o.z; m.w += o.w;
            lds[threadIdx.x] = m;
        }
        __syncthreads();
    }
    if (threadIdx.x < 4)
        ((float4*)(pp + (size_t)rh * HH))[cg * 4 + threadIdx.x] = lds[threadIdx.x];
}

// 2048 blocks x 256 threads: one row per wave. scores[row] = enc[row,:].(pp0+pp1)
__global__ void __launch_bounds__(256) rowdot_kernel(
    const float* __restrict__ enc,
    const float* __restrict__ pp,
    float* __restrict__ scores)
{
    const int wave = threadIdx.x >> 6;
    const int lane = threadIdx.x & 63;
    const int row  = blockIdx.x * 4 + wave;

    const float4* p0 = (const float4*)pp;
    const float4* p1 = (const float4*)(pp + HH);
    const float4* e  = (const float4*)(enc + (size_t)row * HH);

    float acc = 0.0f;
#pragma unroll
    for (int i = 0; i < 8; ++i) {          // 512 float4 per row / 64 lanes
        const float4 a  = e[lane + i * 64];
        const float4 b0 = p0[lane + i * 64];
        const float4 b1 = p1[lane + i * 64];
        acc += a.x * (b0.x + b1.x) + a.y * (b0.y + b1.y)
             + a.z * (b0.z + b1.z) + a.w * (b0.w + b1.w);
    }
#pragma unroll
    for (int off = 32; off > 0; off >>= 1)
        acc += __shfl_down(acc, off);
    if (lane == 0) scores[row] = acc;
}

// single block, 1024 threads, 8 elems/thread; two-pass softmax scores -> out
__global__ void __launch_bounds__(1024) softmax_kernel(
    const float* __restrict__ scores,
    float* __restrict__ out)
{
    __shared__ float red[16];
    const int tid  = threadIdx.x;
    const int lane = tid & 63;
    const int wid  = tid >> 6;             // 16 waves

    float vals[8];
    float m = -INFINITY;
#pragma unroll
    for (int i = 0; i < 8; ++i) {
        vals[i] = scores[tid + i * 1024];
        m = fmaxf(m, vals[i]);
    }
#pragma unroll
    for (int off = 1; off < 64; off <<= 1)
        m = fmaxf(m, __shfl_xor(m, off));
    if (lane == 0) red[wid] = m;
    __syncthreads();
#pragma unroll
    for (int i = 0; i < 16; ++i) m = fmaxf(m, red[i]);

    float s = 0.0f;
#pragma unroll
    for (int i = 0; i < 8; ++i) {
        vals[i] = __expf(vals[i] - m);
        s += vals[i];
    }
#pragma unroll
    for (int off = 1; off < 64; off <<= 1)
        s += __shfl_xor(s, off);
    __syncthreads();                       // done reading red (max phase)
    if (lane == 0) red[wid] = s;
    __syncthreads();
    float tot = 0.0f;
#pragma unroll
    for (int i = 0; i < 16; ++i) tot += red[i];

    const float inv = 1.0f / tot;
#pragma unroll
    for (int i = 0; i < 8; ++i)
        out[tid + i * 1024] = vals[i] * inv;
}

extern "C" void kernel_launch(void* const* d_in, const int* in_sizes, int n_in,
                              void* d_out, int out_size, void* d_ws, size_t ws_size,
                              hipStream_t stream) {
    const float* enc   = (const float*)d_in[0];  // (S,1,H)
    // d_in[1] = hidden : constant score shift, cancels in softmax
    const float* W_att = (const float*)d_in[2];  // (H, 2H)
    // d_in[3] = b_att  : constant score shift, cancels
    const float* w     = (const float*)d_in[4];  // (1, H)

    float* out    = (float*)d_out;               // 8192 floats
    float* ws     = (float*)d_ws;
    float* pp     = ws;                          // 2*2048 floats
    float* scores = ws + 2 * HH;                 // 8192 floats

    hipLaunchKernelGGL(colsum_kernel,  dim3(256),  dim3(256),  0, stream, W_att, w, pp);
    hipLaunchKernelGGL(rowdot_kernel,  dim3(2048), dim3(256),  0, stream, enc, pp, scores);
    hipLaunchKernelGGL(softmax_kernel, dim3(1),    dim3(1024), 0, stream, scores, out);
}